// Round 1
// baseline (2140.078 us; speedup 1.0000x reference)
//
#include <hip/hip_runtime.h>
#include <stdint.h>

// Quantizer (VQ) on MI355X.
// T=32768 tokens, K=8192 codes, C=256. All fp32.
// Round 0: exact-fp32 baseline. dist = (||x||^2 - 2 x.e) + ||e||^2 (reference
// expansion order), argmin via packed (dist_bits<<32)|k u64 atomicMin
// (monotonic for positive floats; tie -> smaller k == np.argmin).
//
// ws layout (needs 416 KB):
//   [0,       262144)  u64 packed[32768]   (init 0xFF = +inf)
//   [262144,  294912)  f32 e2[8192]
//   [294912,  425984)  f32 x2[32768]

#define T_TOT 32768
#define K_TOT 8192
#define CD    256
#define BT    128
#define BK    128
#define KSPLIT 2
#define KRANGE (K_TOT / KSPLIT)
#define NT_BLK (T_TOT / BT)          // 256 t-tiles

__device__ __forceinline__ unsigned long long shfl_xor_u64(unsigned long long v, int off, int w) {
  unsigned lo = (unsigned)v, hi = (unsigned)(v >> 32);
  lo = __shfl_xor(lo, off, w);
  hi = __shfl_xor(hi, off, w);
  return ((unsigned long long)hi << 32) | lo;
}

// data[t,c] = in[(t>>10)*262144 + c*1024 + (t&1023)]  (NCHW -> [T,C] transpose)

__global__ __launch_bounds__(256) void norms_kernel(const float* __restrict__ in,
                                                    const float* __restrict__ cb,
                                                    float* __restrict__ e2,
                                                    float* __restrict__ x2) {
  const int b = blockIdx.x;
  const int tid = threadIdx.x;
  if (b < 2048) {                       // codebook norms: 4 rows/block, wave per row
    const int wave = tid >> 6, lane = tid & 63;
    const int row = b * 4 + wave;
    const float4 v = *(const float4*)(cb + row * CD + lane * 4);
    float s = v.x * v.x + v.y * v.y + v.z * v.z + v.w * v.w;
    #pragma unroll
    for (int off = 32; off >= 1; off >>= 1) s += __shfl_down(s, off, 64);
    if (lane == 0) e2[row] = s;
  } else {                              // token norms: 256 consecutive t per block
    const int t = (b - 2048) * 256 + tid;
    const float* p = in + ((t >> 10) << 18) + (t & 1023);
    float s = 0.f;
    #pragma unroll 8
    for (int c = 0; c < CD; ++c) { const float v = p[c << 10]; s += v * v; }
    x2[t] = s;
  }
}

__global__ __launch_bounds__(256) void dist_argmin_kernel(
    const float* __restrict__ in, const float* __restrict__ cb,
    const float* __restrict__ e2, const float* __restrict__ x2,
    unsigned long long* __restrict__ packed) {
  __shared__ __align__(16) float As[32][BT];   // [c-chunk][token]
  __shared__ __align__(16) float Bs[32][BK];   // [c-chunk][code]

  const int tid = threadIdx.x;
  const int tx = tid & 15, ty = tid >> 4;
  const int tb = blockIdx.x & (NT_BLK - 1);
  const int ks = blockIdx.x >> 8;              // K-split id (0..KSPLIT-1)
  const int t0 = tb * BT;
  const int nbase = (t0 >> 10) << 18;
  const int tin = t0 & 1023;

  float xi[8];
  #pragma unroll
  for (int i = 0; i < 8; ++i)
    xi[i] = x2[t0 + ty * 4 + (i & 3) + ((i >> 2) << 6)];

  unsigned long long best[8];
  #pragma unroll
  for (int i = 0; i < 8; ++i) best[i] = ~0ull;

  for (int kt = 0; kt < KRANGE / BK; ++kt) {
    const int k0 = ks * KRANGE + kt * BK;

    float acc[8][8];
    #pragma unroll
    for (int i = 0; i < 8; ++i)
      #pragma unroll
      for (int j = 0; j < 8; ++j) acc[i][j] = 0.f;

    float ej[8];
    #pragma unroll
    for (int j = 0; j < 8; ++j)
      ej[j] = e2[k0 + tx * 4 + (j & 3) + ((j >> 2) << 6)];

    for (int ch = 0; ch < 8; ++ch) {
      const int c0 = ch * 32;
      // stage A tile: 32c x 128t
      #pragma unroll
      for (int p = 0; p < 4; ++p) {
        const int l = p * 1024 + tid * 4;
        const int cc = l >> 7, tt = l & 127;
        *(float4*)&As[cc][tt] =
            *(const float4*)(in + nbase + (c0 + cc) * 1024 + tin + tt);
      }
      // stage B tile (transposed store): 32c x 128k
      #pragma unroll
      for (int p = 0; p < 4; ++p) {
        const int idx = p * 256 + tid;
        const int kk = idx >> 3, cs = (idx & 7) * 4;
        const float4 v = *(const float4*)(cb + (k0 + kk) * CD + c0 + cs);
        Bs[cs + 0][kk] = v.x; Bs[cs + 1][kk] = v.y;
        Bs[cs + 2][kk] = v.z; Bs[cs + 3][kk] = v.w;
      }
      __syncthreads();
      #pragma unroll
      for (int cc = 0; cc < 32; ++cc) {
        const float4 a0 = *(const float4*)&As[cc][ty * 4];
        const float4 a1 = *(const float4*)&As[cc][64 + ty * 4];
        const float4 b0 = *(const float4*)&Bs[cc][tx * 4];
        const float4 b1 = *(const float4*)&Bs[cc][64 + tx * 4];
        const float a[8]  = {a0.x, a0.y, a0.z, a0.w, a1.x, a1.y, a1.z, a1.w};
        const float bb[8] = {b0.x, b0.y, b0.z, b0.w, b1.x, b1.y, b1.z, b1.w};
        #pragma unroll
        for (int i = 0; i < 8; ++i)
          #pragma unroll
          for (int j = 0; j < 8; ++j)
            acc[i][j] += a[i] * bb[j];
      }
      __syncthreads();
    }

    // epilogue: dist + running packed min
    #pragma unroll
    for (int i = 0; i < 8; ++i) {
      unsigned long long m = best[i];
      #pragma unroll
      for (int j = 0; j < 8; ++j) {
        const float dist = (xi[i] - 2.0f * acc[i][j]) + ej[j];
        const int kidx = k0 + tx * 4 + (j & 3) + ((j >> 2) << 6);
        const unsigned long long pk =
            ((unsigned long long)__float_as_uint(dist) << 32) | (unsigned)kidx;
        m = pk < m ? pk : m;
      }
      best[i] = m;
    }
  }

  // reduce over the 16 tx lanes (same ty group within wave), then atomicMin
  #pragma unroll
  for (int i = 0; i < 8; ++i) {
    unsigned long long m = best[i];
    #pragma unroll
    for (int off = 8; off >= 1; off >>= 1) {
      const unsigned long long o = shfl_xor_u64(m, off, 16);
      m = o < m ? o : m;
    }
    if (tx == 0)
      atomicMin(&packed[t0 + ty * 4 + (i & 3) + ((i >> 2) << 6)], m);
  }
}

__global__ __launch_bounds__(256) void output_kernel(
    const float* __restrict__ in, const float* __restrict__ cb,
    const unsigned long long* __restrict__ packed, float* __restrict__ out) {
  __shared__ float Ds[32][257];
  __shared__ int idxs[32];
  const int tid = threadIdx.x;
  const int t0 = blockIdx.x * 32;
  const int nbase = (t0 >> 10) << 18;
  const int tin = t0 & 1023;

  if (tid < 32) idxs[tid] = (int)(packed[t0 + tid] & 0xffffffffull);
  #pragma unroll 8
  for (int p = 0; p < 32; ++p) {
    const int lin = p * 256 + tid;
    const int cc = lin >> 5, tt = lin & 31;
    Ds[tt][cc] = in[nbase + cc * 1024 + tin + tt];
  }
  __syncthreads();

  float* out1 = out;
  float* out2 = out + 8388608;
  float* out3 = out + 16777216;
  for (int tt = 0; tt < 32; ++tt) {
    const float d = Ds[tt][tid];
    const int k = idxs[tt];
    const float q = cb[k * CD + tid];
    const float qd = d + (q - d);      // reference order: data + (quantize - data)
    const int o = (t0 + tt) * CD + tid;
    out1[o] = q;
    out2[o] = qd;
    out3[o] = d;
  }
}

extern "C" void kernel_launch(void* const* d_in, const int* in_sizes, int n_in,
                              void* d_out, int out_size, void* d_ws, size_t ws_size,
                              hipStream_t stream) {
  const float* in = (const float*)d_in[0];
  const float* cb = (const float*)d_in[1];
  float* out = (float*)d_out;

  unsigned long long* packed = (unsigned long long*)d_ws;
  float* e2 = (float*)((char*)d_ws + 262144);
  float* x2 = (float*)((char*)d_ws + 294912);

  hipMemsetAsync(packed, 0xFF, T_TOT * sizeof(unsigned long long), stream);
  norms_kernel<<<2176, 256, 0, stream>>>(in, cb, e2, x2);
  dist_argmin_kernel<<<NT_BLK * KSPLIT, 256, 0, stream>>>(in, cb, e2, x2, packed);
  output_kernel<<<T_TOT / 32, 256, 0, stream>>>(in, cb, packed, out);
}

// Round 2
// 482.463 us; speedup vs baseline: 4.4357x; 4.4357x over previous
//
#include <hip/hip_runtime.h>
#include <stdint.h>

// VQ Quantizer on MI355X. T=32768 tokens, K=8192 codes, C=256, fp32 in/out.
// Round 1: fp16 MFMA screening (top-2 per K-split) + exact fp32 rescore.
//   dist argmin screened on u = 0.5*e2 + 256 - x.e  (monotone in dist, >0).
//   u32 key = (f32bits(u) & ~63) | local_idx  -> v_min_u32 top-2 tracking.
//   Candidates: 4 splits x top2 = 8/token, rescored exactly in fp32.

#define T_TOT 32768
#define K_TOT 8192
#define CD    256
#define SPLITS 4
#define NSPLIT 2048
#define NTILES 16            // N-tiles of 128 per split

typedef _Float16 h8 __attribute__((ext_vector_type(8)));
typedef _Float16 h4 __attribute__((ext_vector_type(4)));
typedef _Float16 h2 __attribute__((ext_vector_type(2)));
typedef float f4 __attribute__((ext_vector_type(4)));
typedef unsigned long long u64;
typedef unsigned int u32;

// ---------------- ws layout (main path, 22.2 MB) ----------------
#define WS_A16   0u            // _Float16 [32768][256]   16 MB
#define WS_B16   16777216u     // _Float16 [8192][256]     4 MB
#define WS_E2    20971520u     // float [8192]
#define WS_E2B   21004288u     // float [8192]  (0.5*e2 + 256)
#define WS_CAND  21037056u     // u64 [32768][4][2]        2 MB
#define WS_IDX   23134208u     // int [32768]
#define WS_NEED  23265280u

__device__ __forceinline__ u64 shfl_xor_u64(u64 v, int off, int w) {
  unsigned lo = (unsigned)v, hi = (unsigned)(v >> 32);
  lo = __shfl_xor(lo, off, w);
  hi = __shfl_xor(hi, off, w);
  return ((u64)hi << 32) | lo;
}
__device__ __forceinline__ u64 umin64(u64 a, u64 b) { return a < b ? a : b; }
__device__ __forceinline__ u64 umax64(u64 a, u64 b) { return a < b ? b : a; }

__device__ __forceinline__ void gll16(const void* g, void* l) {
  __builtin_amdgcn_global_load_lds(
      (const __attribute__((address_space(1))) void*)g,
      (__attribute__((address_space(3))) void*)l, 16, 0, 0);
}

// data[t,c] = in[(t>>10)*262144 + c*1024 + (t&1023)]  (NCHW -> [T,C])

// ============ main path kernels ============

// NCHW fp32 -> [T,C] fp16 (LDS transpose)
__global__ __launch_bounds__(256) void cvt_data_kernel(
    const float* __restrict__ in, _Float16* __restrict__ A16) {
  __shared__ float Ds[32][257];
  const int tid = threadIdx.x;
  const int t0 = blockIdx.x * 32;
  const int nbase = (t0 >> 10) << 18;
  const int tin = t0 & 1023;
  #pragma unroll 8
  for (int p = 0; p < 32; ++p) {
    const int lin = p * 256 + tid;
    const int cc = lin >> 5, tt = lin & 31;
    Ds[tt][cc] = in[nbase + cc * 1024 + tin + tt];
  }
  __syncthreads();
  if (tid < 128) {
    for (int tt = 0; tt < 32; ++tt) {
      h2 hv;
      hv[0] = (_Float16)Ds[tt][tid * 2];
      hv[1] = (_Float16)Ds[tt][tid * 2 + 1];
      *(h2*)(A16 + (t0 + tt) * CD + tid * 2) = hv;
    }
  }
}

// codebook fp32 -> fp16, plus e2 (exact fp32) and e2b = 0.5*e2 + 256
__global__ __launch_bounds__(256) void cvt_cb_kernel(
    const float* __restrict__ cb, _Float16* __restrict__ B16,
    float* __restrict__ e2, float* __restrict__ e2b) {
  const int tid = threadIdx.x;
  const int w = tid >> 6, lane = tid & 63;
  const int row = blockIdx.x * 4 + w;
  const float4 v = *(const float4*)(cb + row * CD + lane * 4);
  h4 hv; hv[0] = (_Float16)v.x; hv[1] = (_Float16)v.y;
  hv[2] = (_Float16)v.z; hv[3] = (_Float16)v.w;
  *(h4*)(B16 + row * CD + lane * 4) = hv;
  float s = v.x * v.x + v.y * v.y + v.z * v.z + v.w * v.w;
  #pragma unroll
  for (int off = 32; off >= 1; off >>= 1) s += __shfl_xor(s, off, 64);
  if (lane == 0) { e2[row] = s; e2b[row] = 0.5f * s + 256.0f; }
}

// fp16 MFMA screen: per (128-token block, split) -> top-2 candidates
__global__ __launch_bounds__(256) void screen_kernel(
    const _Float16* __restrict__ A, const _Float16* __restrict__ B,
    const float* __restrict__ e2b, u64* __restrict__ cand) {
  __shared__ __align__(16) _Float16 smem[16384];  // 32 KB: As[128][64] + Bs[128][64], XOR-swizzled
  _Float16* As = smem;
  _Float16* Bs = smem + 8192;

  const int tid = threadIdx.x;
  const int lane = tid & 63;
  const int w = tid >> 6;
  const int wrow = (w >> 1) * 64;   // wave row offset in 128-tile
  const int wn = w & 1;             // wave col half
  const int q = lane >> 4;
  const int c15 = lane & 15;

  const int bm = blockIdx.x & 255;
  const int split = blockIdx.x >> 8;
  const int t0 = bm * 128;
  const int n0s = split * NSPLIT;

  // staging lane geometry (swizzle: lane l carries global chunk (l&7)^(l>>3),
  // lands at LDS chunk l&7 of row (l>>3) -> LDS holds chunk c at pos c^(row&7))
  const int srow = lane >> 3;
  const int schunk = (lane & 7) ^ srow;

  u32 m1[16], m2[16];
  #pragma unroll
  for (int r = 0; r < 16; ++r) { m1[r] = 0xffffffffu; m2[r] = 0xffffffffu; }

  for (int nt = 0; nt < NTILES; ++nt) {
    const int n0 = n0s + nt * 128;
    f4 acc[4][4];
    #pragma unroll
    for (int mi = 0; mi < 4; ++mi)
      #pragma unroll
      for (int nj = 0; nj < 4; ++nj) acc[mi][nj] = (f4)0.0f;

    for (int ck = 0; ck < 4; ++ck) {
      const int c0 = ck * 64;
      __syncthreads();   // previous chunk's frag reads done before overwrite
      #pragma unroll
      for (int s = 0; s < 4; ++s) {
        const int i = w * 4 + s;                       // instr id 0..15
        gll16(A + (t0 + i * 8 + srow) * CD + c0 + schunk * 8, As + i * 512);
        gll16(B + (n0 + i * 8 + srow) * CD + c0 + schunk * 8, Bs + i * 512);
      }
      __syncthreads();
      #pragma unroll
      for (int kk = 0; kk < 2; ++kk) {
        h8 af[4], bf[4];
        #pragma unroll
        for (int mi = 0; mi < 4; ++mi) {
          const int m = wrow + mi * 16 + c15;
          af[mi] = *(const h8*)(As + m * 64 + ((((kk << 2) + q) ^ (m & 7)) << 3));
        }
        #pragma unroll
        for (int nj = 0; nj < 4; ++nj) {
          const int n = wn * 64 + nj * 16 + c15;
          bf[nj] = *(const h8*)(Bs + n * 64 + ((((kk << 2) + q) ^ (n & 7)) << 3));
        }
        #pragma unroll
        for (int mi = 0; mi < 4; ++mi)
          #pragma unroll
          for (int nj = 0; nj < 4; ++nj)
            acc[mi][nj] = __builtin_amdgcn_mfma_f32_16x16x32_f16(
                af[mi], bf[nj], acc[mi][nj], 0, 0, 0);
      }
    }

    // epilogue: u = e2b - acc, pack local idx in low 6 bits, track top-2
    float ev[4];
    #pragma unroll
    for (int nj = 0; nj < 4; ++nj)
      ev[nj] = e2b[n0 + wn * 64 + nj * 16 + c15];
    #pragma unroll
    for (int mi = 0; mi < 4; ++mi)
      #pragma unroll
      for (int nj = 0; nj < 4; ++nj) {
        const u32 lidx = (u32)(nt * 4 + nj);
        #pragma unroll
        for (int reg = 0; reg < 4; ++reg) {
          const float u = ev[nj] - acc[mi][nj][reg];
          const u32 key = (__float_as_uint(u) & ~63u) | lidx;
          const int r = mi * 4 + reg;
          const u32 lo = min(m1[r], key);
          const u32 hi = max(m1[r], key);
          m1[r] = lo;
          m2[r] = min(m2[r], hi);
        }
      }
  }

  // merge: per-lane top2 -> per-row top2 across 16 lanes, then across waves
  u64 P1[16], P2[16];
  #pragma unroll
  for (int r = 0; r < 16; ++r) {
    const u32 l1 = m1[r] & 63u, l2 = m2[r] & 63u;
    const u32 col1 = (u32)(n0s + ((l1 >> 2) << 7) + (wn << 6) + ((l1 & 3) << 4) + c15);
    const u32 col2 = (u32)(n0s + ((l2 >> 2) << 7) + (wn << 6) + ((l2 & 3) << 4) + c15);
    P1[r] = ((u64)m1[r] << 32) | col1;
    P2[r] = ((u64)m2[r] << 32) | col2;
  }
  #pragma unroll
  for (int st = 1; st < 16; st <<= 1) {
    #pragma unroll
    for (int r = 0; r < 16; ++r) {
      const u64 o1 = shfl_xor_u64(P1[r], st, 16);
      const u64 o2 = shfl_xor_u64(P2[r], st, 16);
      const u64 n1 = umin64(P1[r], o1);
      const u64 hi = umax64(P1[r], o1);
      P2[r] = umin64(hi, umin64(P2[r], o2));
      P1[r] = n1;
    }
  }

  __syncthreads();           // all frag reads done; reuse smem as merge buffer
  u64* buf = (u64*)smem;     // [2][128][2]
  #pragma unroll
  for (int r = 0; r < 16; ++r) {
    if (c15 == r) {
      const int row = wrow + ((r >> 2) << 4) + (q << 2) + (r & 3);
      buf[(wn * 128 + row) * 2 + 0] = P1[r];
      buf[(wn * 128 + row) * 2 + 1] = P2[r];
    }
  }
  __syncthreads();
  if (tid < 128) {
    const u64 a1 = buf[tid * 2], a2 = buf[tid * 2 + 1];
    const u64 b1 = buf[(128 + tid) * 2], b2 = buf[(128 + tid) * 2 + 1];
    const u64 n1 = umin64(a1, b1);
    const u64 n2 = umin64(umax64(a1, b1), umin64(a2, b2));
    cand[(u64)(t0 + tid) * 8 + split * 2 + 0] = n1;
    cand[(u64)(t0 + tid) * 8 + split * 2 + 1] = n2;
  }
}

// exact fp32 rescore of 8 candidates/token (x^2 term cancels in argmin)
__global__ __launch_bounds__(256) void rescore_kernel(
    const float* __restrict__ in, const float* __restrict__ cb,
    const float* __restrict__ e2, const u64* __restrict__ cand,
    int* __restrict__ idx) {
  __shared__ __align__(16) float Ds[32][260];
  const int tid = threadIdx.x;
  const int t0 = blockIdx.x * 32;
  const int nbase = (t0 >> 10) << 18;
  const int tin = t0 & 1023;
  #pragma unroll 8
  for (int p = 0; p < 32; ++p) {
    const int lin = p * 256 + tid;
    const int cc = lin >> 5, tt = lin & 31;
    Ds[tt][cc] = in[nbase + cc * 1024 + tin + tt];
  }
  __syncthreads();
  const int w = tid >> 6, lane = tid & 63;
  for (int s = 0; s < 8; ++s) {
    const int tt = w * 8 + s;
    const int t = t0 + tt;
    int colv = 0;
    if (lane < 8) colv = (int)(u32)cand[(u64)t * 8 + lane];
    const float4 x = *(const float4*)&Ds[tt][lane * 4];
    float bestd = 1e30f; int bestc = 0x7fffffff;
    #pragma unroll
    for (int j = 0; j < 8; ++j) {
      const int col = __shfl(colv, j, 64);
      const float4 e = *(const float4*)(cb + (u64)col * CD + lane * 4);
      float p4 = x.x * e.x + x.y * e.y + x.z * e.z + x.w * e.w;
      #pragma unroll
      for (int off = 32; off >= 1; off >>= 1) p4 += __shfl_xor(p4, off, 64);
      const float d = e2[col] - 2.0f * p4;
      if (d < bestd || (d == bestd && col < bestc)) { bestd = d; bestc = col; }
    }
    if (lane == 0) idx[t] = bestc;
  }
}

__global__ __launch_bounds__(256) void output_idx_kernel(
    const float* __restrict__ in, const float* __restrict__ cb,
    const int* __restrict__ idxarr, float* __restrict__ out) {
  __shared__ float Ds[32][257];
  __shared__ int idxs[32];
  const int tid = threadIdx.x;
  const int t0 = blockIdx.x * 32;
  const int nbase = (t0 >> 10) << 18;
  const int tin = t0 & 1023;
  if (tid < 32) idxs[tid] = idxarr[t0 + tid];
  #pragma unroll 8
  for (int p = 0; p < 32; ++p) {
    const int lin = p * 256 + tid;
    const int cc = lin >> 5, tt = lin & 31;
    Ds[tt][cc] = in[nbase + cc * 1024 + tin + tt];
  }
  __syncthreads();
  float* out1 = out;
  float* out2 = out + 8388608;
  float* out3 = out + 16777216;
  for (int tt = 0; tt < 32; ++tt) {
    const float d = Ds[tt][tid];
    const int k = idxs[tt];
    const float q = cb[k * CD + tid];
    const float qd = d + (q - d);
    const int o = (t0 + tt) * CD + tid;
    out1[o] = q;
    out2[o] = qd;
    out3[o] = d;
  }
}

// ============ fallback path (round-0 exact fp32), used if ws too small ============

__global__ __launch_bounds__(256) void norms_kernel(const float* __restrict__ in,
                                                    const float* __restrict__ cb,
                                                    float* __restrict__ e2,
                                                    float* __restrict__ x2) {
  const int b = blockIdx.x;
  const int tid = threadIdx.x;
  if (b < 2048) {
    const int wave = tid >> 6, lane = tid & 63;
    const int row = b * 4 + wave;
    const float4 v = *(const float4*)(cb + row * CD + lane * 4);
    float s = v.x * v.x + v.y * v.y + v.z * v.z + v.w * v.w;
    #pragma unroll
    for (int off = 32; off >= 1; off >>= 1) s += __shfl_down(s, off, 64);
    if (lane == 0) e2[row] = s;
  } else {
    const int t = (b - 2048) * 256 + tid;
    const float* p = in + ((t >> 10) << 18) + (t & 1023);
    float s = 0.f;
    #pragma unroll 8
    for (int c = 0; c < CD; ++c) { const float v = p[c << 10]; s += v * v; }
    x2[t] = s;
  }
}

__global__ __launch_bounds__(256) void dist_argmin_kernel(
    const float* __restrict__ in, const float* __restrict__ cb,
    const float* __restrict__ e2, const float* __restrict__ x2,
    u64* __restrict__ packed) {
  __shared__ __align__(16) float As_[32][128];
  __shared__ __align__(16) float Bs_[32][128];
  const int tid = threadIdx.x;
  const int tx = tid & 15, ty = tid >> 4;
  const int tb = blockIdx.x & 255;
  const int ks = blockIdx.x >> 8;
  const int t0 = tb * 128;
  const int nbase = (t0 >> 10) << 18;
  const int tin = t0 & 1023;
  float xi[8];
  #pragma unroll
  for (int i = 0; i < 8; ++i)
    xi[i] = x2[t0 + ty * 4 + (i & 3) + ((i >> 2) << 6)];
  u64 best[8];
  #pragma unroll
  for (int i = 0; i < 8; ++i) best[i] = ~0ull;
  for (int kt = 0; kt < 32; ++kt) {
    const int k0 = ks * 4096 + kt * 128;
    float acc[8][8];
    #pragma unroll
    for (int i = 0; i < 8; ++i)
      #pragma unroll
      for (int j = 0; j < 8; ++j) acc[i][j] = 0.f;
    float ej[8];
    #pragma unroll
    for (int j = 0; j < 8; ++j)
      ej[j] = e2[k0 + tx * 4 + (j & 3) + ((j >> 2) << 6)];
    for (int ch = 0; ch < 8; ++ch) {
      const int c0 = ch * 32;
      #pragma unroll
      for (int p = 0; p < 4; ++p) {
        const int l = p * 1024 + tid * 4;
        const int cc = l >> 7, tt = l & 127;
        *(float4*)&As_[cc][tt] =
            *(const float4*)(in + nbase + (c0 + cc) * 1024 + tin + tt);
      }
      #pragma unroll
      for (int p = 0; p < 4; ++p) {
        const int ix = p * 256 + tid;
        const int kk = ix >> 3, cs = (ix & 7) * 4;
        const float4 v = *(const float4*)(cb + (k0 + kk) * CD + c0 + cs);
        Bs_[cs + 0][kk] = v.x; Bs_[cs + 1][kk] = v.y;
        Bs_[cs + 2][kk] = v.z; Bs_[cs + 3][kk] = v.w;
      }
      __syncthreads();
      #pragma unroll
      for (int cc = 0; cc < 32; ++cc) {
        const float4 a0 = *(const float4*)&As_[cc][ty * 4];
        const float4 a1 = *(const float4*)&As_[cc][64 + ty * 4];
        const float4 b0 = *(const float4*)&Bs_[cc][tx * 4];
        const float4 b1 = *(const float4*)&Bs_[cc][64 + tx * 4];
        const float a[8]  = {a0.x, a0.y, a0.z, a0.w, a1.x, a1.y, a1.z, a1.w};
        const float bb[8] = {b0.x, b0.y, b0.z, b0.w, b1.x, b1.y, b1.z, b1.w};
        #pragma unroll
        for (int i = 0; i < 8; ++i)
          #pragma unroll
          for (int j = 0; j < 8; ++j)
            acc[i][j] += a[i] * bb[j];
      }
      __syncthreads();
    }
    #pragma unroll
    for (int i = 0; i < 8; ++i) {
      u64 m = best[i];
      #pragma unroll
      for (int j = 0; j < 8; ++j) {
        const float dist = (xi[i] - 2.0f * acc[i][j]) + ej[j];
        const int kidx = k0 + tx * 4 + (j & 3) + ((j >> 2) << 6);
        const u64 pk = ((u64)__float_as_uint(dist) << 32) | (unsigned)kidx;
        m = pk < m ? pk : m;
      }
      best[i] = m;
    }
  }
  #pragma unroll
  for (int i = 0; i < 8; ++i) {
    u64 m = best[i];
    #pragma unroll
    for (int off = 8; off >= 1; off >>= 1) {
      const u64 o = shfl_xor_u64(m, off, 16);
      m = o < m ? o : m;
    }
    if (tx == 0)
      atomicMin(&packed[t0 + ty * 4 + (i & 3) + ((i >> 2) << 6)], m);
  }
}

__global__ __launch_bounds__(256) void output_kernel(
    const float* __restrict__ in, const float* __restrict__ cb,
    const u64* __restrict__ packed, float* __restrict__ out) {
  __shared__ float Ds[32][257];
  __shared__ int idxs[32];
  const int tid = threadIdx.x;
  const int t0 = blockIdx.x * 32;
  const int nbase = (t0 >> 10) << 18;
  const int tin = t0 & 1023;
  if (tid < 32) idxs[tid] = (int)(packed[t0 + tid] & 0xffffffffull);
  #pragma unroll 8
  for (int p = 0; p < 32; ++p) {
    const int lin = p * 256 + tid;
    const int cc = lin >> 5, tt = lin & 31;
    Ds[tt][cc] = in[nbase + cc * 1024 + tin + tt];
  }
  __syncthreads();
  float* out1 = out;
  float* out2 = out + 8388608;
  float* out3 = out + 16777216;
  for (int tt = 0; tt < 32; ++tt) {
    const float d = Ds[tt][tid];
    const int k = idxs[tt];
    const float q = cb[k * CD + tid];
    const float qd = d + (q - d);
    const int o = (t0 + tt) * CD + tid;
    out1[o] = q;
    out2[o] = qd;
    out3[o] = d;
  }
}

extern "C" void kernel_launch(void* const* d_in, const int* in_sizes, int n_in,
                              void* d_out, int out_size, void* d_ws, size_t ws_size,
                              hipStream_t stream) {
  const float* in = (const float*)d_in[0];
  const float* cb = (const float*)d_in[1];
  float* out = (float*)d_out;

  if (ws_size >= WS_NEED) {
    _Float16* A16 = (_Float16*)((char*)d_ws + WS_A16);
    _Float16* B16 = (_Float16*)((char*)d_ws + WS_B16);
    float* e2  = (float*)((char*)d_ws + WS_E2);
    float* e2b = (float*)((char*)d_ws + WS_E2B);
    u64* cand  = (u64*)((char*)d_ws + WS_CAND);
    int* idx   = (int*)((char*)d_ws + WS_IDX);

    cvt_data_kernel<<<T_TOT / 32, 256, 0, stream>>>(in, A16);
    cvt_cb_kernel<<<K_TOT / 4, 256, 0, stream>>>(cb, B16, e2, e2b);
    screen_kernel<<<256 * SPLITS, 256, 0, stream>>>(A16, B16, e2b, cand);
    rescore_kernel<<<T_TOT / 32, 256, 0, stream>>>(in, cb, e2, cand, idx);
    output_idx_kernel<<<T_TOT / 32, 256, 0, stream>>>(in, cb, idx, out);
  } else {
    u64* packed = (u64*)d_ws;
    float* e2 = (float*)((char*)d_ws + 262144);
    float* x2 = (float*)((char*)d_ws + 294912);
    hipMemsetAsync(packed, 0xFF, T_TOT * sizeof(u64), stream);
    norms_kernel<<<2176, 256, 0, stream>>>(in, cb, e2, x2);
    dist_argmin_kernel<<<512, 256, 0, stream>>>(in, cb, e2, x2, packed);
    output_kernel<<<T_TOT / 32, 256, 0, stream>>>(in, cb, packed, out);
  }
}

// Round 3
// 336.546 us; speedup vs baseline: 6.3589x; 1.4336x over previous
//
#include <hip/hip_runtime.h>
#include <stdint.h>

// VQ Quantizer on MI355X. T=32768 tokens, K=8192 codes, C=256, fp32 in/out.
// Round 3: pipelined fp16 MFMA screen (A-frags persistent in VGPRs, B double-
// buffered, 1 barrier/iter, e2b in MFMA C-init) + fused rescore+output.
//   screen key u = 0.5*e2 + 256 - x.e  (A16 stores -x so acc = e2b + (-x).e)
//   u32 key = (f32bits(u) & ~63) | (nt<<1|nj); top-2 per split; exact rescore.

#define T_TOT 32768
#define K_TOT 8192
#define CD    256
#define SPLITS 4
#define NSPLIT 2048
#define MT    64            // tokens per screen block
#define NTI   32            // B-tiles of 64 codes per split
#define BHALF 16384         // halfs per LDS buffer (64 rows x 256)

typedef _Float16 h8 __attribute__((ext_vector_type(8)));
typedef _Float16 h4 __attribute__((ext_vector_type(4)));
typedef _Float16 h2 __attribute__((ext_vector_type(2)));
typedef float f4 __attribute__((ext_vector_type(4)));
typedef unsigned long long u64;
typedef unsigned int u32;

// ---------------- ws layout ----------------
#define WS_A16   0u            // _Float16 [32768][256]   16 MB   (NEGATED data)
#define WS_B16   16777216u     // _Float16 [8192][256]     4 MB
#define WS_E2    20971520u     // float [8192]
#define WS_E2B   21004288u     // float [8192]  (0.5*e2 + 256)
#define WS_CAND  21037056u     // u64 [32768][4][2]        2 MB
#define WS_NEED  23265280u

__device__ __forceinline__ u64 shfl_xor_u64(u64 v, int off, int w) {
  unsigned lo = (unsigned)v, hi = (unsigned)(v >> 32);
  lo = __shfl_xor(lo, off, w);
  hi = __shfl_xor(hi, off, w);
  return ((u64)hi << 32) | lo;
}
__device__ __forceinline__ u64 umin64(u64 a, u64 b) { return a < b ? a : b; }
__device__ __forceinline__ u64 umax64(u64 a, u64 b) { return a < b ? b : a; }
__device__ __forceinline__ u32 umin32(u32 a, u32 b) { return a < b ? a : b; }
__device__ __forceinline__ u32 umax32(u32 a, u32 b) { return a < b ? b : a; }

__device__ __forceinline__ void gll16(const void* g, void* l) {
  __builtin_amdgcn_global_load_lds(
      (const __attribute__((address_space(1))) void*)g,
      (__attribute__((address_space(3))) void*)l, 16, 0, 0);
}

// stage a 64-row x 256-half tile with XOR(row&7) chunk swizzle.
// LDS: slot s (16B) of row r holds global chunk s^(r&7).
__device__ __forceinline__ void stage_tile(const _Float16* __restrict__ gsrc,
                                           _Float16* lbase, int w, int lane) {
  const int lrow = lane >> 5, lslot = lane & 31;
  #pragma unroll
  for (int s = 0; s < 8; ++s) {
    const int r0 = s * 8 + w * 2;
    const int r = r0 + lrow;
    const int chunk = lslot ^ (r & 7);
    gll16(gsrc + (u64)r * CD + chunk * 8, lbase + r0 * CD);
  }
}

// data[t,c] = in[(t>>10)*262144 + c*1024 + (t&1023)]  (NCHW -> [T,C])

// ============ main path ============

// NCHW fp32 -> [T,C] fp16, NEGATED (so screen acc = e2b - x.e directly)
__global__ __launch_bounds__(256) void cvt_data_kernel(
    const float* __restrict__ in, _Float16* __restrict__ A16) {
  __shared__ float Ds[32][257];
  const int tid = threadIdx.x;
  const int t0 = blockIdx.x * 32;
  const int nbase = (t0 >> 10) << 18;
  const int tin = t0 & 1023;
  #pragma unroll 8
  for (int p = 0; p < 32; ++p) {
    const int lin = p * 256 + tid;
    const int cc = lin >> 5, tt = lin & 31;
    Ds[tt][cc] = in[nbase + cc * 1024 + tin + tt];
  }
  __syncthreads();
  if (tid < 128) {
    for (int tt = 0; tt < 32; ++tt) {
      h2 hv;
      hv[0] = (_Float16)(-Ds[tt][tid * 2]);
      hv[1] = (_Float16)(-Ds[tt][tid * 2 + 1]);
      *(h2*)(A16 + (t0 + tt) * CD + tid * 2) = hv;
    }
  }
}

// codebook fp32 -> fp16, e2 exact, e2b = 0.5*e2 + 256
__global__ __launch_bounds__(256) void cvt_cb_kernel(
    const float* __restrict__ cb, _Float16* __restrict__ B16,
    float* __restrict__ e2, float* __restrict__ e2b) {
  const int tid = threadIdx.x;
  const int w = tid >> 6, lane = tid & 63;
  const int row = blockIdx.x * 4 + w;
  const float4 v = *(const float4*)(cb + row * CD + lane * 4);
  h4 hv; hv[0] = (_Float16)v.x; hv[1] = (_Float16)v.y;
  hv[2] = (_Float16)v.z; hv[3] = (_Float16)v.w;
  *(h4*)(B16 + row * CD + lane * 4) = hv;
  float s = v.x * v.x + v.y * v.y + v.z * v.z + v.w * v.w;
  #pragma unroll
  for (int off = 32; off >= 1; off >>= 1) s += __shfl_xor(s, off, 64);
  if (lane == 0) { e2[row] = s; e2b[row] = 0.5f * s + 256.0f; }
}

// pipelined fp16 MFMA screen: 64 tokens x 2048 codes per block -> top-2
__global__ __launch_bounds__(256, 2) void screen_kernel(
    const _Float16* __restrict__ A, const _Float16* __restrict__ B,
    const float* __restrict__ e2b, u64* __restrict__ cand) {
  __shared__ __align__(16) _Float16 smem[2 * BHALF];   // 64 KB

  const int tid = threadIdx.x;
  const int lane = tid & 63;
  const int w = tid >> 6;          // 0..3
  const int wrg = w >> 1;          // token rows [wrg*32, +32)
  const int wcg = w & 1;           // code cols  [wcg*32, +32) within nt tile
  const int q = lane >> 4;
  const int c15 = lane & 15;
  const int sx = c15 & 7;          // frag-read swizzle (rows have r&7 == c15&7)

  const int bm = blockIdx.x & 511;
  const int split = blockIdx.x >> 9;
  const int t0 = bm * MT;
  const int n0s = split * NSPLIT;

  _Float16* buf0 = smem;
  _Float16* buf1 = smem + BHALF;

  // ---- prologue: A tile -> buf0, frags -> regs; B(0) -> buf1 ----
  stage_tile(A + (u64)t0 * CD, buf0, w, lane);
  __syncthreads();                         // drain A gll16s

  h8 af[2][8];
  {
    const int m0 = wrg * 32 + c15;
    #pragma unroll
    for (int mi = 0; mi < 2; ++mi) {
      const int m = m0 + mi * 16;
      #pragma unroll
      for (int kk = 0; kk < 8; ++kk) {
        const int slot = (kk * 4 + q) ^ sx;
        af[mi][kk] = *(const h8*)(buf0 + m * CD + slot * 8);
      }
    }
  }
  stage_tile(B + (u64)n0s * CD, buf1, w, lane);

  const float* e2bs = e2b + n0s + wcg * 32 + c15;   // + nj*16 + nt*64
  float ev0 = e2bs[0], ev1 = e2bs[16];

  u32 m1[8], m2[8];
  #pragma unroll
  for (int r = 0; r < 8; ++r) { m1[r] = 0xffffffffu; m2[r] = 0xffffffffu; }

  __syncthreads();    // drain B(0) gll16s + all A frag reads done

  const int nb0 = wcg * 32 + c15;
  for (int nt = 0; nt < NTI; ++nt) {
    _Float16* cur = (nt & 1) ? buf0 : buf1;
    _Float16* nxt = (nt & 1) ? buf1 : buf0;

    if (nt < NTI - 1)                       // prefetch next B tile
      stage_tile(B + (u64)(n0s + (nt + 1) * 64) * CD, nxt, w, lane);
    const int ntn = (nt < NTI - 1) ? (nt + 1) * 64 : nt * 64;
    const float evn0 = e2bs[ntn];
    const float evn1 = e2bs[ntn + 16];

    f4 acc[2][2];
    #pragma unroll
    for (int mi = 0; mi < 2; ++mi) {
      acc[mi][0] = (f4){ev0, ev0, ev0, ev0};
      acc[mi][1] = (f4){ev1, ev1, ev1, ev1};
    }
    #pragma unroll
    for (int kk = 0; kk < 8; ++kk) {
      const int slot = (kk * 4 + q) ^ sx;
      const h8 b0 = *(const h8*)(cur + nb0 * CD + slot * 8);
      const h8 b1 = *(const h8*)(cur + (nb0 + 16) * CD + slot * 8);
      acc[0][0] = __builtin_amdgcn_mfma_f32_16x16x32_f16(af[0][kk], b0, acc[0][0], 0, 0, 0);
      acc[1][0] = __builtin_amdgcn_mfma_f32_16x16x32_f16(af[1][kk], b0, acc[1][0], 0, 0, 0);
      acc[0][1] = __builtin_amdgcn_mfma_f32_16x16x32_f16(af[0][kk], b1, acc[0][1], 0, 0, 0);
      acc[1][1] = __builtin_amdgcn_mfma_f32_16x16x32_f16(af[1][kk], b1, acc[1][1], 0, 0, 0);
    }

    // top-2 insert: 2 values (nj=0/1) per row r
    #pragma unroll
    for (int mi = 0; mi < 2; ++mi)
      #pragma unroll
      for (int reg = 0; reg < 4; ++reg) {
        const int r = mi * 4 + reg;
        const u32 k0 = (__float_as_uint(acc[mi][0][reg]) & ~63u) | (u32)(nt * 2);
        const u32 k1 = (__float_as_uint(acc[mi][1][reg]) & ~63u) | (u32)(nt * 2 + 1);
        const u32 lo = umin32(k0, k1), hi = umax32(k0, k1);
        const u32 t = umax32(m1[r], lo);
        m1[r] = umin32(m1[r], lo);
        m2[r] = umin32(m2[r], umin32(hi, t));
      }
    ev0 = evn0; ev1 = evn1;
    __syncthreads();    // everyone done reading cur; our nxt loads drained
  }

  // ---- merge: 16 lanes (same quad) -> per-row top2, then across wcg ----
  u64 P1[8], P2[8];
  #pragma unroll
  for (int r = 0; r < 8; ++r) {
    const u32 l1 = m1[r] & 63u, l2 = m2[r] & 63u;
    const u32 col1 = (u32)(n0s + (l1 >> 1) * 64 + wcg * 32 + (l1 & 1) * 16 + c15);
    const u32 col2 = (u32)(n0s + (l2 >> 1) * 64 + wcg * 32 + (l2 & 1) * 16 + c15);
    P1[r] = ((u64)m1[r] << 32) | col1;
    P2[r] = ((u64)m2[r] << 32) | col2;
  }
  #pragma unroll
  for (int st = 1; st < 16; st <<= 1) {
    #pragma unroll
    for (int r = 0; r < 8; ++r) {
      const u64 o1 = shfl_xor_u64(P1[r], st, 16);
      const u64 o2 = shfl_xor_u64(P2[r], st, 16);
      const u64 n1 = umin64(P1[r], o1);
      const u64 hi = umax64(P1[r], o1);
      P2[r] = umin64(hi, umin64(P2[r], o2));
      P1[r] = n1;
    }
  }

  u64* mbuf = (u64*)smem;        // [2 wcg][64 rows][2]
  if (c15 == 0) {
    #pragma unroll
    for (int r = 0; r < 8; ++r) {
      const int mi = r >> 2, reg = r & 3;
      const int row = wrg * 32 + mi * 16 + q * 4 + reg;
      mbuf[(wcg * 64 + row) * 2 + 0] = P1[r];
      mbuf[(wcg * 64 + row) * 2 + 1] = P2[r];
    }
  }
  __syncthreads();
  if (tid < 64) {
    const u64 a1 = mbuf[tid * 2], a2 = mbuf[tid * 2 + 1];
    const u64 b1 = mbuf[(64 + tid) * 2], b2 = mbuf[(64 + tid) * 2 + 1];
    const u64 n1 = umin64(a1, b1);
    const u64 n2 = umin64(umax64(a1, b1), umin64(a2, b2));
    cand[(u64)(t0 + tid) * 8 + split * 2 + 0] = n1;
    cand[(u64)(t0 + tid) * 8 + split * 2 + 1] = n2;
  }
}

// fused: exact fp32 rescore of 8 candidates + write all 3 outputs
__global__ __launch_bounds__(256) void rescore_output_kernel(
    const float* __restrict__ in, const float* __restrict__ cb,
    const float* __restrict__ e2, const u64* __restrict__ cand,
    float* __restrict__ out) {
  __shared__ __align__(16) float Ds[32][260];
  __shared__ int idxs[32];
  const int tid = threadIdx.x;
  const int t0 = blockIdx.x * 32;
  const int nbase = (t0 >> 10) << 18;
  const int tin = t0 & 1023;
  #pragma unroll 8
  for (int p = 0; p < 32; ++p) {
    const int lin = p * 256 + tid;
    const int cc = lin >> 5, tt = lin & 31;
    Ds[tt][cc] = in[nbase + cc * 1024 + tin + tt];
  }
  __syncthreads();
  const int w = tid >> 6, lane = tid & 63;
  for (int s = 0; s < 8; ++s) {
    const int tt = w * 8 + s;
    const int t = t0 + tt;
    int colv = 0;
    if (lane < 8) colv = (int)(u32)cand[(u64)t * 8 + lane];
    const float4 x = *(const float4*)&Ds[tt][lane * 4];
    float bestd = 1e30f; int bestc = 0x7fffffff;
    #pragma unroll
    for (int j = 0; j < 8; ++j) {
      const int col = __shfl(colv, j, 64);
      const float4 e = *(const float4*)(cb + (u64)col * CD + lane * 4);
      float p4 = x.x * e.x + x.y * e.y + x.z * e.z + x.w * e.w;
      #pragma unroll
      for (int off = 32; off >= 1; off >>= 1) p4 += __shfl_xor(p4, off, 64);
      const float d = e2[col] - 2.0f * p4;
      if (d < bestd || (d == bestd && col < bestc)) { bestd = d; bestc = col; }
    }
    if (lane == 0) idxs[tt] = bestc;
  }
  __syncthreads();
  float* out1 = out;
  float* out2 = out + 8388608;
  float* out3 = out + 16777216;
  for (int tt = 0; tt < 32; ++tt) {
    const float d = Ds[tt][tid];
    const int k = idxs[tt];
    const float qv = cb[k * CD + tid];
    const float qd = d + (qv - d);
    const int o = (t0 + tt) * CD + tid;
    out1[o] = qv;
    out2[o] = qd;
    out3[o] = d;
  }
}

// ============ fallback path (exact fp32), used if ws too small ============

__global__ __launch_bounds__(256) void norms_kernel(const float* __restrict__ in,
                                                    const float* __restrict__ cb,
                                                    float* __restrict__ e2,
                                                    float* __restrict__ x2) {
  const int b = blockIdx.x;
  const int tid = threadIdx.x;
  if (b < 2048) {
    const int wave = tid >> 6, lane = tid & 63;
    const int row = b * 4 + wave;
    const float4 v = *(const float4*)(cb + row * CD + lane * 4);
    float s = v.x * v.x + v.y * v.y + v.z * v.z + v.w * v.w;
    #pragma unroll
    for (int off = 32; off >= 1; off >>= 1) s += __shfl_down(s, off, 64);
    if (lane == 0) e2[row] = s;
  } else {
    const int t = (b - 2048) * 256 + tid;
    const float* p = in + ((t >> 10) << 18) + (t & 1023);
    float s = 0.f;
    #pragma unroll 8
    for (int c = 0; c < CD; ++c) { const float v = p[c << 10]; s += v * v; }
    x2[t] = s;
  }
}

__global__ __launch_bounds__(256) void dist_argmin_kernel(
    const float* __restrict__ in, const float* __restrict__ cb,
    const float* __restrict__ e2, const float* __restrict__ x2,
    u64* __restrict__ packed) {
  __shared__ __align__(16) float As_[32][128];
  __shared__ __align__(16) float Bs_[32][128];
  const int tid = threadIdx.x;
  const int tx = tid & 15, ty = tid >> 4;
  const int tb = blockIdx.x & 255;
  const int ks = blockIdx.x >> 8;
  const int t0 = tb * 128;
  const int nbase = (t0 >> 10) << 18;
  const int tin = t0 & 1023;
  float xi[8];
  #pragma unroll
  for (int i = 0; i < 8; ++i)
    xi[i] = x2[t0 + ty * 4 + (i & 3) + ((i >> 2) << 6)];
  u64 best[8];
  #pragma unroll
  for (int i = 0; i < 8; ++i) best[i] = ~0ull;
  for (int kt = 0; kt < 32; ++kt) {
    const int k0 = ks * 4096 + kt * 128;
    float acc[8][8];
    #pragma unroll
    for (int i = 0; i < 8; ++i)
      #pragma unroll
      for (int j = 0; j < 8; ++j) acc[i][j] = 0.f;
    float ej[8];
    #pragma unroll
    for (int j = 0; j < 8; ++j)
      ej[j] = e2[k0 + tx * 4 + (j & 3) + ((j >> 2) << 6)];
    for (int ch = 0; ch < 8; ++ch) {
      const int c0 = ch * 32;
      #pragma unroll
      for (int p = 0; p < 4; ++p) {
        const int l = p * 1024 + tid * 4;
        const int cc = l >> 7, tt = l & 127;
        *(float4*)&As_[cc][tt] =
            *(const float4*)(in + nbase + (c0 + cc) * 1024 + tin + tt);
      }
      #pragma unroll
      for (int p = 0; p < 4; ++p) {
        const int ix = p * 256 + tid;
        const int kk = ix >> 3, cs = (ix & 7) * 4;
        const float4 v = *(const float4*)(cb + (k0 + kk) * CD + c0 + cs);
        Bs_[cs + 0][kk] = v.x; Bs_[cs + 1][kk] = v.y;
        Bs_[cs + 2][kk] = v.z; Bs_[cs + 3][kk] = v.w;
      }
      __syncthreads();
      #pragma unroll
      for (int cc = 0; cc < 32; ++cc) {
        const float4 a0 = *(const float4*)&As_[cc][ty * 4];
        const float4 a1 = *(const float4*)&As_[cc][64 + ty * 4];
        const float4 b0 = *(const float4*)&Bs_[cc][tx * 4];
        const float4 b1 = *(const float4*)&Bs_[cc][64 + tx * 4];
        const float a[8]  = {a0.x, a0.y, a0.z, a0.w, a1.x, a1.y, a1.z, a1.w};
        const float bb[8] = {b0.x, b0.y, b0.z, b0.w, b1.x, b1.y, b1.z, b1.w};
        #pragma unroll
        for (int i = 0; i < 8; ++i)
          #pragma unroll
          for (int j = 0; j < 8; ++j)
            acc[i][j] += a[i] * bb[j];
      }
      __syncthreads();
    }
    #pragma unroll
    for (int i = 0; i < 8; ++i) {
      u64 m = best[i];
      #pragma unroll
      for (int j = 0; j < 8; ++j) {
        const float dist = (xi[i] - 2.0f * acc[i][j]) + ej[j];
        const int kidx = k0 + tx * 4 + (j & 3) + ((j >> 2) << 6);
        const u64 pk = ((u64)__float_as_uint(dist) << 32) | (unsigned)kidx;
        m = pk < m ? pk : m;
      }
      best[i] = m;
    }
  }
  #pragma unroll
  for (int i = 0; i < 8; ++i) {
    u64 m = best[i];
    #pragma unroll
    for (int off = 8; off >= 1; off >>= 1) {
      const u64 o = shfl_xor_u64(m, off, 16);
      m = o < m ? o : m;
    }
    if (tx == 0)
      atomicMin(&packed[t0 + ty * 4 + (i & 3) + ((i >> 2) << 6)], m);
  }
}

__global__ __launch_bounds__(256) void output_kernel(
    const float* __restrict__ in, const float* __restrict__ cb,
    const u64* __restrict__ packed, float* __restrict__ out) {
  __shared__ float Ds[32][257];
  __shared__ int idxs[32];
  const int tid = threadIdx.x;
  const int t0 = blockIdx.x * 32;
  const int nbase = (t0 >> 10) << 18;
  const int tin = t0 & 1023;
  if (tid < 32) idxs[tid] = (int)(packed[t0 + tid] & 0xffffffffull);
  #pragma unroll 8
  for (int p = 0; p < 32; ++p) {
    const int lin = p * 256 + tid;
    const int cc = lin >> 5, tt = lin & 31;
    Ds[tt][cc] = in[nbase + cc * 1024 + tin + tt];
  }
  __syncthreads();
  float* out1 = out;
  float* out2 = out + 8388608;
  float* out3 = out + 16777216;
  for (int tt = 0; tt < 32; ++tt) {
    const float d = Ds[tt][tid];
    const int k = idxs[tt];
    const float q = cb[k * CD + tid];
    const float qd = d + (q - d);
    const int o = (t0 + tt) * CD + tid;
    out1[o] = q;
    out2[o] = qd;
    out3[o] = d;
  }
}

extern "C" void kernel_launch(void* const* d_in, const int* in_sizes, int n_in,
                              void* d_out, int out_size, void* d_ws, size_t ws_size,
                              hipStream_t stream) {
  const float* in = (const float*)d_in[0];
  const float* cb = (const float*)d_in[1];
  float* out = (float*)d_out;

  if (ws_size >= WS_NEED) {
    _Float16* A16 = (_Float16*)((char*)d_ws + WS_A16);
    _Float16* B16 = (_Float16*)((char*)d_ws + WS_B16);
    float* e2  = (float*)((char*)d_ws + WS_E2);
    float* e2b = (float*)((char*)d_ws + WS_E2B);
    u64* cand  = (u64*)((char*)d_ws + WS_CAND);

    cvt_data_kernel<<<T_TOT / 32, 256, 0, stream>>>(in, A16);
    cvt_cb_kernel<<<K_TOT / 4, 256, 0, stream>>>(cb, B16, e2, e2b);
    screen_kernel<<<(T_TOT / MT) * SPLITS, 256, 0, stream>>>(A16, B16, e2b, cand);
    rescore_output_kernel<<<T_TOT / 32, 256, 0, stream>>>(in, cb, e2, cand, out);
  } else {
    u64* packed = (u64*)d_ws;
    float* e2 = (float*)((char*)d_ws + 262144);
    float* x2 = (float*)((char*)d_ws + 294912);
    hipMemsetAsync(packed, 0xFF, T_TOT * sizeof(u64), stream);
    norms_kernel<<<2176, 256, 0, stream>>>(in, cb, e2, x2);
    dist_argmin_kernel<<<512, 256, 0, stream>>>(in, cb, e2, x2, packed);
    output_kernel<<<T_TOT / 32, 256, 0, stream>>>(in, cb, packed, out);
  }
}